// Round 7
// baseline (302.934 us; speedup 1.0000x reference)
//
#include <hip/hip_runtime.h>
#include <hip/hip_bf16.h>

// EvenOddFunctionHAM: out = rho(rho(s)@W + b_odd + [Ux|0]) @ W^T + b_even
// R6 -> R7: revert to R3's proven schedule (4 phases x 2 barriers, 2 LDS
// bufs, vmcnt(4)); single change: MFMA shape 16x16x32 -> 32x32x16
// (+14.8% measured ceiling, half the MFMA issue slots, same ds_read
// pattern). Plus post-loop vmcnt(0) tail drain (cross-block LDS safety).

#define N_DIM 4096
#define D1_DIM 2048

typedef short short8 __attribute__((ext_vector_type(8)));
typedef float f32x16 __attribute__((ext_vector_type(16)));

__device__ __forceinline__ float rho_f(float x) {
    return 1.0f / (1.0f + __expf(2.0f - 4.0f * x));  // sigmoid(4x-2)
}

__device__ __forceinline__ unsigned short f2bf(float x) {
    unsigned int u = __builtin_bit_cast(unsigned int, x);
    u += 0x7fffu + ((u >> 16) & 1u);
    return (unsigned short)(u >> 16);
}

__device__ __forceinline__ void gl_lds16(const unsigned short* g, void* l) {
    __builtin_amdgcn_global_load_lds(
        (const __attribute__((address_space(1))) void*)g,
        (__attribute__((address_space(3))) void*)l, 16, 0, 0);
}

// ---------------- prep: Rs = bf16(rho(s)) ----------------
__global__ void prep_rs_kernel(const float* __restrict__ s,
                               unsigned short* __restrict__ Rs, int n8) {
    int t = blockIdx.x * blockDim.x + threadIdx.x;
    int stride = gridDim.x * blockDim.x;
    for (int i = t; i < n8; i += stride) {
        float4 a = ((const float4*)s)[2 * i];
        float4 b = ((const float4*)s)[2 * i + 1];
        unsigned int r0 = f2bf(rho_f(a.x)) | ((unsigned int)f2bf(rho_f(a.y)) << 16);
        unsigned int r1 = f2bf(rho_f(a.z)) | ((unsigned int)f2bf(rho_f(a.w)) << 16);
        unsigned int r2 = f2bf(rho_f(b.x)) | ((unsigned int)f2bf(rho_f(b.y)) << 16);
        unsigned int r3 = f2bf(rho_f(b.z)) | ((unsigned int)f2bf(rho_f(b.w)) << 16);
        uint4 o; o.x = r0; o.y = r1; o.z = r2; o.w = r3;
        ((uint4*)Rs)[i] = o;
    }
}

// ------- prep: Wb = bf16(W); WTb = transpose. Block (1,0) of W is never
// read by either GEMM's K-ranges -> skip it (mask input unused). -------
__global__ void prep_w_kernel(const float* __restrict__ W,
                              unsigned short* __restrict__ Wb,
                              unsigned short* __restrict__ WTb) {
    if (blockIdx.y * 32 >= D1_DIM && blockIdx.x * 32 < D1_DIM) return;  // dead
    __shared__ unsigned short t[32][33];
    int x = blockIdx.x * 32 + threadIdx.x;
    #pragma unroll
    for (int r = 0; r < 4; r++) {
        int y = blockIdx.y * 32 + threadIdx.y + r * 8;
        size_t idx = (size_t)y * N_DIM + x;
        unsigned short b = f2bf(W[idx]);
        Wb[idx] = b;
        t[threadIdx.y + r * 8][threadIdx.x] = b;
    }
    __syncthreads();
    #pragma unroll
    for (int r = 0; r < 4; r++) {
        int yy = threadIdx.y + r * 8;
        int orow = blockIdx.x * 32 + yy;
        int ocol = blockIdx.y * 32 + threadIdx.x;
        WTb[(size_t)orow * N_DIM + ocol] = t[threadIdx.x][yy];
    }
}

// ---------------- GEMM 256x256, BK=64, 8 waves, 4 phases/K-tile ----------
// C = A @ Bt^T. A[M][K], Bt[N][K] bf16 row-major (ld=4096), fp32 acc.
// MFMA 32x32x16: A-frag lane l = A[row=l&31][k=(l>>5)*8 .. +7];
// C/D: col=lane&31, row=(reg&3)+8*(reg>>2)+4*(lane>>5).
// LDS per buf (64KB): A[256][64] at 0, B[256][64] at 32768; 2 bufs.
// Stage A(t+1) at p1-p2 -> buf c^1; B(t+2) at p3-p4 -> buf c (slots free).
// vmcnt(4) at p4 = tile t+1 complete, t+2's B in flight (FIFO-exact).
// Swizzle: LDS[r][chunk c] = G[r][c ^ (r&7)], source-side + read-side.
template<int MODE>
__global__ __launch_bounds__(512, 2) void gemm_kernel(
    const unsigned short* __restrict__ A,
    const unsigned short* __restrict__ Bt,
    void* __restrict__ Out,
    const float* __restrict__ Ux,
    const float* __restrict__ bias) {
    __shared__ __align__(16) char lds[131072];

    // XCD remap: XCD x gets tile-rows {2x, 2x+1}
    const int id = blockIdx.x;
    const int wg = ((id & 7) << 5) | (id >> 3);
    const int by = wg >> 4, bx = wg & 15;
    const int brow = by << 8, bcol = bx << 8;

    const int tid = threadIdx.x;
    const int w = tid >> 6;
    const int L = tid & 63;
    const int wr = w >> 2;         // 0..1 : rows wr*128..+127
    const int wc = w & 3;          // 0..3 : cols wc*64..+63
    const int l31 = L & 31;
    const int lhi = L >> 5;        // 0..1
    const int swz = L & 7;

    // block-sparse K range (exact: skipped W blocks are all-zero)
    int kbeg, kend;
    if (MODE == 1) { kbeg = 0; kend = (bcol < D1_DIM) ? D1_DIM : N_DIM; }
    else           { kbeg = (bcol < D1_DIM) ? 0 : D1_DIM; kend = N_DIM; }

    // ---- staging: half-tile = 128 rows x 64 cols = 16KB, 2 gl_lds/thread
    const int srow8 = w * 16 + (L >> 3);
    const int scol = ((L & 7) ^ (L >> 3)) << 3;
#define STAGE_HALF(mat, gbase, h, kt, bb, isB) do {                            \
        const unsigned short* gs_ = (mat) +                                    \
            (size_t)((gbase) + (h) * 128 + srow8) * N_DIM +                    \
            (kbeg + ((kt) << 6) + scol);                                       \
        char* ld_ = lds + (bb) * 65536 + (isB) * 32768 + (h) * 16384 + w * 2048;\
        gl_lds16(gs_, ld_);                                                    \
        gl_lds16(gs_ + 8 * N_DIM, ld_ + 1024);                                 \
    } while (0)

    short8 af[2][4], bf0[4], bf1[4];
#define LDA(bb, qm) do {                                                       \
        _Pragma("unroll") for (int mt_ = 0; mt_ < 2; ++mt_)                    \
        _Pragma("unroll") for (int ks_ = 0; ks_ < 4; ++ks_) {                  \
            const int R_ = wr * 128 + (qm) * 64 + mt_ * 32 + l31;              \
            af[mt_][ks_] = *(const short8*)(lds + (bb) * 65536 + R_ * 128 +    \
                (((ks_ * 2 + lhi) ^ swz) << 4)); }                             \
    } while (0)
#define LDB(bb, qn, dst) do {                                                  \
        _Pragma("unroll") for (int ks_ = 0; ks_ < 4; ++ks_) {                  \
            const int R_ = wc * 64 + (qn) * 32 + l31;                          \
            dst[ks_] = *(const short8*)(lds + (bb) * 65536 + 32768 +           \
                R_ * 128 + (((ks_ * 2 + lhi) ^ swz) << 4)); }                  \
    } while (0)

    f32x16 acc[4][2];   // [qm*2+mt][qn]
    #pragma unroll
    for (int i = 0; i < 4; i++)
        #pragma unroll
        for (int j = 0; j < 2; j++)
            acc[i][j] = (f32x16)(0.f);

#define MFMA_Q(qm, qn, bfr) do {                                               \
        __builtin_amdgcn_s_setprio(1);                                         \
        _Pragma("unroll") for (int mt_ = 0; mt_ < 2; ++mt_)                    \
        _Pragma("unroll") for (int ks_ = 0; ks_ < 4; ++ks_)                    \
            acc[(qm) * 2 + mt_][qn] =                                          \
                __builtin_amdgcn_mfma_f32_32x32x16_bf16(                       \
                    af[mt_][ks_], bfr[ks_], acc[(qm) * 2 + mt_][qn], 0, 0, 0); \
        __builtin_amdgcn_s_setprio(0);                                         \
    } while (0)

#define LGKM0() do { asm volatile("s_waitcnt lgkmcnt(0)" ::: "memory");        \
                     __builtin_amdgcn_sched_barrier(0); } while (0)
#define BAR() __builtin_amdgcn_s_barrier()

    const int nk = (kend - kbeg) >> 6;   // 32 or 64 (power of 2)
    const int km = nk - 1;

    // ---- prologue: t0 fully + t1.B halves; leaves exactly 4 loads in flight
    STAGE_HALF(A, brow, 0, 0, 0, 0);
    STAGE_HALF(A, brow, 1, 0, 0, 0);
    STAGE_HALF(Bt, bcol, 0, 0, 0, 1);
    STAGE_HALF(Bt, bcol, 1, 0, 0, 1);
    STAGE_HALF(Bt, bcol, 0, 1 & km, 1, 1);
    STAGE_HALF(Bt, bcol, 1, 1 & km, 1, 1);
    asm volatile("s_waitcnt vmcnt(4)" ::: "memory");
    BAR();

    for (int t = 0; t < nk; ++t) {
        const int c = t & 1;
        const int t1 = (t + 1) & km;     // wrapped tail: valid addr, dead buf
        const int t2 = (t + 2) & km;

        // phase 1: quad (0,0); stage next-tile A half0 -> buf c^1
        LDA(c, 0); LDB(c, 0, bf0);
        STAGE_HALF(A, brow, 0, t1, c ^ 1, 0);
        BAR();
        LGKM0();
        MFMA_Q(0, 0, bf0);
        BAR();

        // phase 2: quad (0,1); stage next-tile A half1
        LDB(c, 1, bf1);
        STAGE_HALF(A, brow, 1, t1, c ^ 1, 0);
        BAR();
        LGKM0();
        MFMA_Q(0, 1, bf1);
        BAR();

        // phase 3: quad (1,0); stage tile t+2's B half0 -> buf c
        LDA(c, 1);
        STAGE_HALF(Bt, bcol, 0, t2, c, 1);
        BAR();
        LGKM0();
        MFMA_Q(1, 0, bf0);
        BAR();

        // phase 4: quad (1,1); stage tile t+2's B half1; counted vmcnt:
        // completes tile t+1 entirely, leaves t+2's 2 B-halves in flight
        STAGE_HALF(Bt, bcol, 1, t2, c, 1);
        asm volatile("s_waitcnt vmcnt(4)" ::: "memory");
        BAR();
        LGKM0();
        MFMA_Q(1, 1, bf1);
        BAR();
    }
    // drain dead tail stages: must not land in the NEXT block's LDS
    asm volatile("s_waitcnt vmcnt(0)" ::: "memory");

    // ---- epilogue: 32x32 C/D: col=lane&31, row=(reg&3)+8*(reg>>2)+4*lhi --
    const bool hasUx = (MODE == 1) && (bcol < D1_DIM);
    #pragma unroll
    for (int mt4 = 0; mt4 < 4; ++mt4) {
        const int rowTile = brow + wr * 128 + mt4 * 32;
        #pragma unroll
        for (int qn = 0; qn < 2; ++qn) {
            const int col = bcol + wc * 64 + qn * 32 + l31;
            const float bv = bias[col];
            #pragma unroll
            for (int reg = 0; reg < 16; ++reg) {
                const int row = rowTile + (reg & 3) + 8 * (reg >> 2) + 4 * lhi;
                float v = acc[mt4][qn][reg] + bv;
                if (MODE == 1) {
                    if (hasUx) v += Ux[(size_t)row * D1_DIM + col];
                    ((unsigned short*)Out)[(size_t)row * N_DIM + col] =
                        f2bf(rho_f(v));
                } else {
                    ((float*)Out)[(size_t)row * N_DIM + col] = v;
                }
            }
        }
    }
#undef STAGE_HALF
#undef LDA
#undef LDB
#undef MFMA_Q
#undef LGKM0
#undef BAR
}

extern "C" void kernel_launch(void* const* d_in, const int* in_sizes, int n_in,
                              void* d_out, int out_size, void* d_ws, size_t ws_size,
                              hipStream_t stream) {
    const float* Ux     = (const float*)d_in[0];  // [4096][2048]
    const float* s      = (const float*)d_in[1];  // [4096][4096]
    const float* W      = (const float*)d_in[2];  // [4096][4096]
    const float* b_even = (const float*)d_in[3];  // [4096]
    const float* b_odd  = (const float*)d_in[4];  // [4096]
    // d_in[5] = W_mask: unused (masked block is never read)

    char* ws = (char*)d_ws;
    const size_t SZ = (size_t)N_DIM * N_DIM * 2;  // 32 MB per bf16 matrix
    unsigned short* Rs  = (unsigned short*)(ws);
    unsigned short* R2  = (unsigned short*)(ws + SZ);
    unsigned short* Wb  = (unsigned short*)(ws + 2 * SZ);
    unsigned short* WTb = (unsigned short*)(ws + 3 * SZ);

    prep_rs_kernel<<<2048, 256, 0, stream>>>(s, Rs, (N_DIM * N_DIM) / 8);
    prep_w_kernel<<<dim3(128, 128), dim3(32, 8), 0, stream>>>(W, Wb, WTb);
    // GEMM1: s_odd = Rs @ W  (+b_odd, +Ux, rho) -> R2 bf16
    gemm_kernel<1><<<256, 512, 0, stream>>>(Rs, WTb, (void*)R2, Ux, b_odd);
    // GEMM2: out = R2 @ W^T (+b_even) -> d_out f32
    gemm_kernel<2><<<256, 512, 0, stream>>>(R2, Wb, d_out, Ux, b_even);
}

// Round 8
// 264.906 us; speedup vs baseline: 1.1436x; 1.1436x over previous
//
#include <hip/hip_runtime.h>
#include <hip/hip_bf16.h>

// EvenOddFunctionHAM: out = rho(rho(s)@W + b_odd + [Ux|0]) @ W^T + b_even
// R7 -> R8: revert 32x32 MFMA (bank-conflicted, 9.4M); base = R6 (best wall
// 266us: 3xA+2xB LDS bufs, 24 up-front ds_reads, counted lgkmcnt, 2
// barriers/K-tile, vmcnt(8)). Changes: merge the two prep kernels into one
// (one launch boundary fewer, overlapped memory streams); issue A-prefetch
// gl_lds before the ds_read batch.

#define N_DIM 4096
#define D1_DIM 2048

typedef short short8 __attribute__((ext_vector_type(8)));
typedef float f32x4 __attribute__((ext_vector_type(4)));

__device__ __forceinline__ float rho_f(float x) {
    return 1.0f / (1.0f + __expf(2.0f - 4.0f * x));  // sigmoid(4x-2)
}

__device__ __forceinline__ unsigned short f2bf(float x) {
    unsigned int u = __builtin_bit_cast(unsigned int, x);
    u += 0x7fffu + ((u >> 16) & 1u);
    return (unsigned short)(u >> 16);
}

__device__ __forceinline__ void gl_lds16(const unsigned short* g, void* l) {
    __builtin_amdgcn_global_load_lds(
        (const __attribute__((address_space(1))) void*)g,
        (__attribute__((address_space(3))) void*)l, 16, 0, 0);
}

// ---------------- merged prep ----------------
// blocks [0, 16384): W tiles -> Wb = bf16(W), WTb = transpose (skip dead
//   block (1,0): never read by either GEMM's K-ranges; mask input unused).
// blocks [16384, 18432): Rs = bf16(rho(s)), grid-stride, short8-vectorized.
__global__ __launch_bounds__(256) void prep_kernel(
    const float* __restrict__ s, const float* __restrict__ W,
    unsigned short* __restrict__ Rs, unsigned short* __restrict__ Wb,
    unsigned short* __restrict__ WTb) {
    __shared__ unsigned short t[32][33];
    const int id = blockIdx.x;
    if (id < 16384) {
        const int bx = id & 127, by = id >> 7;
        if (by * 32 >= D1_DIM && bx * 32 < D1_DIM) return;  // dead block
        const int tx = threadIdx.x & 31, ty = threadIdx.x >> 5;  // 32 x 8
        const int x = bx * 32 + tx;
        #pragma unroll
        for (int r = 0; r < 4; r++) {
            const int y = by * 32 + ty + r * 8;
            const size_t idx = (size_t)y * N_DIM + x;
            const unsigned short b = f2bf(W[idx]);
            Wb[idx] = b;
            t[ty + r * 8][tx] = b;
        }
        __syncthreads();
        #pragma unroll
        for (int r = 0; r < 4; r++) {
            const int yy = ty + r * 8;
            WTb[(size_t)(bx * 32 + yy) * N_DIM + (by * 32 + tx)] = t[tx][yy];
        }
    } else {
        const int n8 = (N_DIM * N_DIM) / 8;
        const int stride = 2048 * 256;
        for (int i = (id - 16384) * 256 + threadIdx.x; i < n8; i += stride) {
            float4 a = ((const float4*)s)[2 * i];
            float4 b = ((const float4*)s)[2 * i + 1];
            unsigned int r0 = f2bf(rho_f(a.x)) | ((unsigned int)f2bf(rho_f(a.y)) << 16);
            unsigned int r1 = f2bf(rho_f(a.z)) | ((unsigned int)f2bf(rho_f(a.w)) << 16);
            unsigned int r2 = f2bf(rho_f(b.x)) | ((unsigned int)f2bf(rho_f(b.y)) << 16);
            unsigned int r3 = f2bf(rho_f(b.z)) | ((unsigned int)f2bf(rho_f(b.w)) << 16);
            uint4 o; o.x = r0; o.y = r1; o.z = r2; o.w = r3;
            ((uint4*)Rs)[i] = o;
        }
    }
}

// ---------------- GEMM 256x256, BK=64, 8 waves, 2 barriers/K-tile --------
// C = A @ Bt^T. A[M][K], Bt[N][K] bf16 row-major (ld=4096), fp32 acc.
// LDS: A bufs at 0/32K/64K (tile t reads a[t%3], stages A(t+2)->a[(t+2)%3]);
// B bufs at 96K/128K (tile t reads b[t%2], stages B(t+2)->b[t%2] after
// BAR#1). ds_reads issued up front [A0,B0,B1,A1], consumed via counted
// lgkmcnt. vmcnt(8) at tile end drains exactly tile t+1 (FIFO).
// Swizzle: LDS[r][chunk c] = G[r][c ^ (r&7)], source-side + read-side.
template<int MODE>
__global__ __launch_bounds__(512, 2) void gemm_kernel(
    const unsigned short* __restrict__ A,
    const unsigned short* __restrict__ Bt,
    void* __restrict__ Out,
    const float* __restrict__ Ux,
    const float* __restrict__ bias) {
    __shared__ __align__(16) char lds[163840];

    // XCD remap: XCD x gets tile-rows {2x, 2x+1}
    const int id = blockIdx.x;
    const int wg = ((id & 7) << 5) | (id >> 3);
    const int by = wg >> 4, bx = wg & 15;
    const int brow = by << 8, bcol = bx << 8;

    const int tid = threadIdx.x;
    const int w = tid >> 6;
    const int L = tid & 63;
    const int wr = w >> 2;         // 0..1 : rows wr*128..+127
    const int wc = w & 3;          // 0..3 : cols wc*64..+63
    const int fr = L & 15;
    const int fq = L >> 4;
    const int swz = fr & 7;

    // block-sparse K range (exact: skipped W blocks are all-zero)
    int kbeg, kend;
    if (MODE == 1) { kbeg = 0; kend = (bcol < D1_DIM) ? D1_DIM : N_DIM; }
    else           { kbeg = (bcol < D1_DIM) ? 0 : D1_DIM; kend = N_DIM; }

    // staging: one round = 1 gl_lds16/thread = 64 rows x 64 cols (8KB)
    const int srl = w * 8 + (L >> 3);
    const int schunk8 = ((L & 7) ^ (L >> 3)) << 3;
    const int wbase = w * 1024;
#define STAGE2(mat, gb, h, kcol, base) do {                                    \
        const unsigned short* g0_ = (mat) +                                    \
            (size_t)((gb) + (h) * 128 + srl) * N_DIM + (kcol) + schunk8;       \
        gl_lds16(g0_, lds + (base) + (h) * 16384 + wbase);                     \
        gl_lds16(g0_ + 64 * N_DIM, lds + (base) + (h) * 16384 + 8192 + wbase); \
    } while (0)

    short8 af0[2][4], af1[2][4], bf0[2][2], bf1[2][2];
#define LDA_Q(ab, qm, dst) do {                                                \
        _Pragma("unroll") for (int s_ = 0; s_ < 2; ++s_)                       \
        _Pragma("unroll") for (int m_ = 0; m_ < 4; ++m_) {                     \
            const int R_ = wr * 128 + (qm) * 64 + m_ * 16 + fr;                \
            dst[s_][m_] = *(const short8*)(lds + (ab) + R_ * 128 +             \
                (((4 * s_ + fq) ^ swz) << 4)); }                               \
    } while (0)
#define LDB_Q(bb, qn, dst) do {                                                \
        _Pragma("unroll") for (int s_ = 0; s_ < 2; ++s_)                       \
        _Pragma("unroll") for (int n_ = 0; n_ < 2; ++n_) {                     \
            const int R_ = wc * 64 + (qn) * 32 + n_ * 16 + fr;                 \
            dst[s_][n_] = *(const short8*)(lds + (bb) + R_ * 128 +             \
                (((4 * s_ + fq) ^ swz) << 4)); }                               \
    } while (0)

    f32x4 acc[8][4];
    #pragma unroll
    for (int i = 0; i < 8; i++)
        #pragma unroll
        for (int j = 0; j < 4; j++)
            acc[i][j] = (f32x4){0.f, 0.f, 0.f, 0.f};

#define MFMA_Q(afr, bfr, qm, qn) do {                                          \
        __builtin_amdgcn_s_setprio(1);                                         \
        _Pragma("unroll") for (int s_ = 0; s_ < 2; ++s_)                       \
        _Pragma("unroll") for (int m_ = 0; m_ < 4; ++m_)                       \
        _Pragma("unroll") for (int n_ = 0; n_ < 2; ++n_)                       \
            acc[(qm) * 4 + m_][(qn) * 2 + n_] =                                \
                __builtin_amdgcn_mfma_f32_16x16x32_bf16(                       \
                    afr[s_][m_], bfr[s_][n_], acc[(qm) * 4 + m_][(qn) * 2 + n_],\
                    0, 0, 0);                                                  \
        __builtin_amdgcn_s_setprio(0);                                         \
    } while (0)

#define SBAR0() __builtin_amdgcn_sched_barrier(0)
#define LGKM(n) do { asm volatile("s_waitcnt lgkmcnt(" #n ")" ::: "memory");   \
                     SBAR0(); } while (0)
#define BAR() __builtin_amdgcn_s_barrier()

    const int nk = (kend - kbeg) >> 6;   // 32 or 64
    const int km = nk - 1;

    // ---- prologue: A(0),B(0),A(1),B(1) (16 loads, FIFO); t0 ready
    {
        const int k0 = kbeg;
        const int k1 = kbeg + ((1 & km) << 6);
        STAGE2(A, brow, 0, k0, 0);       STAGE2(A, brow, 1, k0, 0);
        STAGE2(Bt, bcol, 0, k0, 98304);  STAGE2(Bt, bcol, 1, k0, 98304);
        STAGE2(A, brow, 0, k1, 32768);   STAGE2(A, brow, 1, k1, 32768);
        STAGE2(Bt, bcol, 0, k1, 131072); STAGE2(Bt, bcol, 1, k1, 131072);
        asm volatile("s_waitcnt vmcnt(8)" ::: "memory");  // A(0),B(0) ready
        BAR();
    }

    int ai = 0, si = 2;                   // a[t%3], a[(t+2)%3]
    for (int t = 0; t < nk; ++t) {
        const int aB = ai * 32768;
        const int sA = si * 32768;
        const int bB = 98304 + (t & 1) * 32768;
        const int ka = kbeg + (((t + 2) & km) << 6);   // wrapped tail: dead

        // stage A(t+2) -> a[(t+2)%3] first (HBM fetch starts earliest;
        // that slot was read iter t-1, safe after its tile-end BAR)
        STAGE2(A, brow, 0, ka, sA);
        STAGE2(A, brow, 1, ka, sA);
        // issue all 24 ds_reads, pinned order: A0(8), B0(4), B1(4), A1(8)
        LDA_Q(aB, 0, af0); SBAR0();
        LDB_Q(bB, 0, bf0); SBAR0();
        LDB_Q(bB, 1, bf1); SBAR0();
        LDA_Q(aB, 1, af1); SBAR0();

        LGKM(12);                      // A0+B0 landed
        MFMA_Q(af0, bf0, 0, 0);
        LGKM(8);                       // +B1 landed (all B reads done)
        MFMA_Q(af0, bf1, 0, 1);
        BAR();                         // #1: all waves' B reads done
        // stage B(t+2) -> b[t%2] (slot just freed)
        STAGE2(Bt, bcol, 0, ka, bB);
        STAGE2(Bt, bcol, 1, ka, bB);
        LGKM(0);                       // +A1 landed
        MFMA_Q(af1, bf0, 1, 0);
        MFMA_Q(af1, bf1, 1, 1);
        // drain exactly tile t+1's 8 loads (FIFO), keep t+2's 8 in flight
        asm volatile("s_waitcnt vmcnt(8)" ::: "memory");
        BAR();                         // #2: tile boundary
        ai++; if (ai == 3) ai = 0;
        si++; if (si == 3) si = 0;
    }
    // drain dead tail stages: must not land in the NEXT block's LDS
    asm volatile("s_waitcnt vmcnt(0)" ::: "memory");

    // ---- epilogue: C/D layout col = fr (N), row = fq*4 + reg (M) ----
    const bool hasUx = (MODE == 1) && (bcol < D1_DIM);
    #pragma unroll
    for (int qm = 0; qm < 2; qm++)
        #pragma unroll
        for (int m = 0; m < 4; m++) {
            const int row0 = brow + wr * 128 + qm * 64 + m * 16 + fq * 4;
            #pragma unroll
            for (int qn = 0; qn < 2; qn++)
                #pragma unroll
                for (int n = 0; n < 2; n++) {
                    const int col = bcol + wc * 64 + qn * 32 + n * 16 + fr;
                    const float bv = bias[col];
                    #pragma unroll
                    for (int r = 0; r < 4; r++) {
                        const int row = row0 + r;
                        float v = acc[qm * 4 + m][qn * 2 + n][r] + bv;
                        if (MODE == 1) {
                            if (hasUx) v += Ux[(size_t)row * D1_DIM + col];
                            ((unsigned short*)Out)[(size_t)row * N_DIM + col] =
                                f2bf(rho_f(v));
                        } else {
                            ((float*)Out)[(size_t)row * N_DIM + col] = v;
                        }
                    }
                }
        }
#undef STAGE2
#undef LDA_Q
#undef LDB_Q
#undef MFMA_Q
#undef SBAR0
#undef LGKM
#undef BAR
}

extern "C" void kernel_launch(void* const* d_in, const int* in_sizes, int n_in,
                              void* d_out, int out_size, void* d_ws, size_t ws_size,
                              hipStream_t stream) {
    const float* Ux     = (const float*)d_in[0];  // [4096][2048]
    const float* s      = (const float*)d_in[1];  // [4096][4096]
    const float* W      = (const float*)d_in[2];  // [4096][4096]
    const float* b_even = (const float*)d_in[3];  // [4096]
    const float* b_odd  = (const float*)d_in[4];  // [4096]
    // d_in[5] = W_mask: unused (masked block is never read)

    char* ws = (char*)d_ws;
    const size_t SZ = (size_t)N_DIM * N_DIM * 2;  // 32 MB per bf16 matrix
    unsigned short* Rs  = (unsigned short*)(ws);
    unsigned short* R2  = (unsigned short*)(ws + SZ);
    unsigned short* Wb  = (unsigned short*)(ws + 2 * SZ);
    unsigned short* WTb = (unsigned short*)(ws + 3 * SZ);

    // merged prep: 16384 W-tile blocks + 2048 rho(s) blocks
    prep_kernel<<<18432, 256, 0, stream>>>(s, W, Rs, Wb, WTb);
    // GEMM1: s_odd = Rs @ W  (+b_odd, +Ux, rho) -> R2 bf16
    gemm_kernel<1><<<256, 512, 0, stream>>>(Rs, WTb, (void*)R2, Ux, b_odd);
    // GEMM2: out = R2 @ W^T (+b_even) -> d_out f32
    gemm_kernel<2><<<256, 512, 0, stream>>>(R2, Wb, d_out, Ux, b_even);
}

// Round 9
// 248.456 us; speedup vs baseline: 1.2193x; 1.0662x over previous
//
#include <hip/hip_runtime.h>
#include <hip/hip_bf16.h>

// EvenOddFunctionHAM: out = rho(rho(s)@W + b_odd + [Ux|0]) @ W^T + b_even
// R8 -> R9: TLP experiment. Same 256x256 tile / BK=64 / 3xA+2xB 160KB LDS /
// chunk-XOR swizzle / counted vmcnt, but 16 waves (1024 thr, 4x4 grid,
// 4 waves/SIMD) instead of 8: cross-wave cover for ds/barrier latency.
// Per-wave: 64x64 out (acc 64 VGPR), A-frags 32, B-frags 16 (reused across
// ks halves) => ~112 VGPR, under the 128/wave cliff at 4 waves/SIMD.

#define N_DIM 4096
#define D1_DIM 2048

typedef short short8 __attribute__((ext_vector_type(8)));
typedef float f32x4 __attribute__((ext_vector_type(4)));

__device__ __forceinline__ float rho_f(float x) {
    return 1.0f / (1.0f + __expf(2.0f - 4.0f * x));  // sigmoid(4x-2)
}

__device__ __forceinline__ unsigned short f2bf(float x) {
    unsigned int u = __builtin_bit_cast(unsigned int, x);
    u += 0x7fffu + ((u >> 16) & 1u);
    return (unsigned short)(u >> 16);
}

__device__ __forceinline__ void gl_lds16(const unsigned short* g, void* l) {
    __builtin_amdgcn_global_load_lds(
        (const __attribute__((address_space(1))) void*)g,
        (__attribute__((address_space(3))) void*)l, 16, 0, 0);
}

// ---------------- merged prep (unchanged from R8) ----------------
__global__ __launch_bounds__(256) void prep_kernel(
    const float* __restrict__ s, const float* __restrict__ W,
    unsigned short* __restrict__ Rs, unsigned short* __restrict__ Wb,
    unsigned short* __restrict__ WTb) {
    __shared__ unsigned short t[32][33];
    const int id = blockIdx.x;
    if (id < 16384) {
        const int bx = id & 127, by = id >> 7;
        if (by * 32 >= D1_DIM && bx * 32 < D1_DIM) return;  // dead block
        const int tx = threadIdx.x & 31, ty = threadIdx.x >> 5;  // 32 x 8
        const int x = bx * 32 + tx;
        #pragma unroll
        for (int r = 0; r < 4; r++) {
            const int y = by * 32 + ty + r * 8;
            const size_t idx = (size_t)y * N_DIM + x;
            const unsigned short b = f2bf(W[idx]);
            Wb[idx] = b;
            t[ty + r * 8][tx] = b;
        }
        __syncthreads();
        #pragma unroll
        for (int r = 0; r < 4; r++) {
            const int yy = ty + r * 8;
            WTb[(size_t)(bx * 32 + yy) * N_DIM + (by * 32 + tx)] = t[tx][yy];
        }
    } else {
        const int n8 = (N_DIM * N_DIM) / 8;
        const int stride = 2048 * 256;
        for (int i = (id - 16384) * 256 + threadIdx.x; i < n8; i += stride) {
            float4 a = ((const float4*)s)[2 * i];
            float4 b = ((const float4*)s)[2 * i + 1];
            unsigned int r0 = f2bf(rho_f(a.x)) | ((unsigned int)f2bf(rho_f(a.y)) << 16);
            unsigned int r1 = f2bf(rho_f(a.z)) | ((unsigned int)f2bf(rho_f(a.w)) << 16);
            unsigned int r2 = f2bf(rho_f(b.x)) | ((unsigned int)f2bf(rho_f(b.y)) << 16);
            unsigned int r3 = f2bf(rho_f(b.z)) | ((unsigned int)f2bf(rho_f(b.w)) << 16);
            uint4 o; o.x = r0; o.y = r1; o.z = r2; o.w = r3;
            ((uint4*)Rs)[i] = o;
        }
    }
}

// ---------------- GEMM 256x256, BK=64, 16 waves (4x4), 4 waves/SIMD ------
// C = A @ Bt^T. A[M][K], Bt[N][K] bf16 row-major (ld=4096), fp32 acc.
// LDS: A bufs 0/32K/64K (tile t reads a[t%3], stage A(t+2)->a[(t+2)%3] at
// tile top); B bufs 96K/128K (tile t reads b[t%2], stage B(t+2)->b[t%2]
// after the post-read barrier). Reads: A0,B0,A1 up-front -> lgkmcnt(4)
// gates MFMA ks0; B1 re-read into same regs after ks0 -> lgkmcnt(0) gates
// ks1. vmcnt(4) at tile end drains exactly tile t+1 (FIFO).
// Swizzle: LDS[r][chunk c] = G[r][c ^ (r&7)], source-side + read-side.
template<int MODE>
__global__ __launch_bounds__(1024, 4) void gemm_kernel(
    const unsigned short* __restrict__ A,
    const unsigned short* __restrict__ Bt,
    void* __restrict__ Out,
    const float* __restrict__ Ux,
    const float* __restrict__ bias) {
    __shared__ __align__(16) char lds[163840];

    // XCD remap: XCD x gets tile-rows {2x, 2x+1}
    const int id = blockIdx.x;
    const int wg = ((id & 7) << 5) | (id >> 3);
    const int by = wg >> 4, bx = wg & 15;
    const int brow = by << 8, bcol = bx << 8;

    const int tid = threadIdx.x;
    const int w = tid >> 6;        // wave 0..15
    const int L = tid & 63;
    const int wr = w >> 2;         // 0..3 : rows wr*64..+63
    const int wc = w & 3;          // 0..3 : cols wc*64..+63
    const int fr = L & 15;
    const int fq = L >> 4;
    const int swz = fr & 7;

    // block-sparse K range (exact: skipped W blocks are all-zero)
    int kbeg, kend;
    if (MODE == 1) { kbeg = 0; kend = (bcol < D1_DIM) ? D1_DIM : N_DIM; }
    else           { kbeg = (bcol < D1_DIM) ? 0 : D1_DIM; kend = N_DIM; }

    // staging: one gl_lds16/thread = 128 rows x 64 cols (16KB); full 256-row
    // matrix tile = 2 instrs. wave w covers rows w*8+(L>>3) (+128 for h=1).
    const int srl = w * 8 + (L >> 3);
    const int schunk8 = ((L & 7) ^ (L >> 3)) << 3;
    const int wbase = w * 1024;
#define STAGEF(mat, gb, kcol, base) do {                                       \
        const unsigned short* g0_ = (mat) +                                    \
            (size_t)((gb) + srl) * N_DIM + (kcol) + schunk8;                   \
        gl_lds16(g0_, lds + (base) + wbase);                                   \
        gl_lds16(g0_ + 128 * N_DIM, lds + (base) + 16384 + wbase);             \
    } while (0)

    short8 af[2][4], bf[4];
#define LDA_K(ab, ks) do {                                                     \
        _Pragma("unroll") for (int m_ = 0; m_ < 4; ++m_) {                     \
            const int R_ = wr * 64 + m_ * 16 + fr;                             \
            af[ks][m_] = *(const short8*)(lds + (ab) + R_ * 128 +              \
                ((((ks) * 4 + fq) ^ swz) << 4)); }                             \
    } while (0)
#define LDB_K(bb, ks) do {                                                     \
        _Pragma("unroll") for (int n_ = 0; n_ < 4; ++n_) {                     \
            const int R_ = wc * 64 + n_ * 16 + fr;                             \
            bf[n_] = *(const short8*)(lds + (bb) + R_ * 128 +                  \
                ((((ks) * 4 + fq) ^ swz) << 4)); }                             \
    } while (0)

    f32x4 acc[4][4];
    #pragma unroll
    for (int i = 0; i < 4; i++)
        #pragma unroll
        for (int j = 0; j < 4; j++)
            acc[i][j] = (f32x4){0.f, 0.f, 0.f, 0.f};

#define MFMA_K(ks) do {                                                        \
        __builtin_amdgcn_s_setprio(1);                                         \
        _Pragma("unroll") for (int m_ = 0; m_ < 4; ++m_)                       \
        _Pragma("unroll") for (int n_ = 0; n_ < 4; ++n_)                       \
            acc[m_][n_] = __builtin_amdgcn_mfma_f32_16x16x32_bf16(             \
                af[ks][m_], bf[n_], acc[m_][n_], 0, 0, 0);                     \
        __builtin_amdgcn_s_setprio(0);                                         \
    } while (0)

#define SBAR0() __builtin_amdgcn_sched_barrier(0)
#define LGKM(n) do { asm volatile("s_waitcnt lgkmcnt(" #n ")" ::: "memory");   \
                     SBAR0(); } while (0)
#define BAR() __builtin_amdgcn_s_barrier()

    const int nk = (kend - kbeg) >> 6;   // 32 or 64
    const int km = nk - 1;

    // ---- prologue: A(0),B(0),A(1),B(1) (8 loads, FIFO); t0 ready
    {
        const int k0 = kbeg;
        const int k1 = kbeg + ((1 & km) << 6);
        STAGEF(A, brow, k0, 0);       STAGEF(Bt, bcol, k0, 98304);
        STAGEF(A, brow, k1, 32768);   STAGEF(Bt, bcol, k1, 131072);
        asm volatile("s_waitcnt vmcnt(4)" ::: "memory");  // A(0),B(0) ready
        BAR();
    }

    int ai = 0, si = 2;                   // a[t%3], a[(t+2)%3]
    for (int t = 0; t < nk; ++t) {
        const int aB = ai * 32768;
        const int sA = si * 32768;
        const int bB = 98304 + (t & 1) * 32768;
        const int ka = kbeg + (((t + 2) & km) << 6);   // wrapped tail: dead

        // stage A(t+2) -> a[(t+2)%3] (slot read iter t-1, drained+barriered)
        STAGEF(A, brow, ka, sA);
        // reads: A0(4), B0(4), A1(4) up-front
        LDA_K(aB, 0); SBAR0();
        LDB_K(bB, 0); SBAR0();
        LDA_K(aB, 1); SBAR0();
        LGKM(4);                       // A0+B0 landed (A1 may be in flight)
        MFMA_K(0);
        LDB_K(bB, 1); SBAR0();         // re-read bf for ks1 (WAR-safe)
        LGKM(0);                       // +A1,B1 landed
        MFMA_K(1);
        BAR();                         // #1: all waves' LDS reads done
        // stage B(t+2) -> b[t%2] (slot just freed)
        STAGEF(Bt, bcol, ka, bB);
        // drain exactly tile t+1's 4 loads (FIFO), keep t+2's 4 in flight
        asm volatile("s_waitcnt vmcnt(4)" ::: "memory");
        BAR();                         // #2: tile boundary
        ai++; if (ai == 3) ai = 0;
        si++; if (si == 3) si = 0;
    }
    // drain dead tail stages: must not land in the NEXT block's LDS
    asm volatile("s_waitcnt vmcnt(0)" ::: "memory");

    // ---- epilogue: C/D layout col = fr (N), row = fq*4 + reg (M) ----
    const bool hasUx = (MODE == 1) && (bcol < D1_DIM);
    #pragma unroll
    for (int m = 0; m < 4; m++) {
        const int row0 = brow + wr * 64 + m * 16 + fq * 4;
        #pragma unroll
        for (int n = 0; n < 4; n++) {
            const int col = bcol + wc * 64 + n * 16 + fr;
            const float bv = bias[col];
            #pragma unroll
            for (int r = 0; r < 4; r++) {
                const int row = row0 + r;
                float v = acc[m][n][r] + bv;
                if (MODE == 1) {
                    if (hasUx) v += Ux[(size_t)row * D1_DIM + col];
                    ((unsigned short*)Out)[(size_t)row * N_DIM + col] =
                        f2bf(rho_f(v));
                } else {
                    ((float*)Out)[(size_t)row * N_DIM + col] = v;
                }
            }
        }
    }
#undef STAGEF
#undef LDA_K
#undef LDB_K
#undef MFMA_K
#undef SBAR0
#undef LGKM
#undef BAR
}

extern "C" void kernel_launch(void* const* d_in, const int* in_sizes, int n_in,
                              void* d_out, int out_size, void* d_ws, size_t ws_size,
                              hipStream_t stream) {
    const float* Ux     = (const float*)d_in[0];  // [4096][2048]
    const float* s      = (const float*)d_in[1];  // [4096][4096]
    const float* W      = (const float*)d_in[2];  // [4096][4096]
    const float* b_even = (const float*)d_in[3];  // [4096]
    const float* b_odd  = (const float*)d_in[4];  // [4096]
    // d_in[5] = W_mask: unused (masked block is never read)

    char* ws = (char*)d_ws;
    const size_t SZ = (size_t)N_DIM * N_DIM * 2;  // 32 MB per bf16 matrix
    unsigned short* Rs  = (unsigned short*)(ws);
    unsigned short* R2  = (unsigned short*)(ws + SZ);
    unsigned short* Wb  = (unsigned short*)(ws + 2 * SZ);
    unsigned short* WTb = (unsigned short*)(ws + 3 * SZ);

    // merged prep: 16384 W-tile blocks + 2048 rho(s) blocks
    prep_kernel<<<18432, 256, 0, stream>>>(s, W, Rs, Wb, WTb);
    // GEMM1: s_odd = Rs @ W  (+b_odd, +Ux, rho) -> R2 bf16
    gemm_kernel<1><<<256, 1024, 0, stream>>>(Rs, WTb, (void*)R2, Ux, b_odd);
    // GEMM2: out = R2 @ W^T (+b_even) -> d_out f32
    gemm_kernel<2><<<256, 1024, 0, stream>>>(R2, Wb, d_out, Ux, b_even);
}